// Round 1
// baseline (1152.302 us; speedup 1.0000x reference)
//
#include <hip/hip_runtime.h>

#define HC 256      // H*C (all three layers output 256)
#define NHEAD 4
#define CDIM 64

// ---------------------------------------------------------------------------
// GEMM: C[M,256] = A[M,K] @ B[K,256], f32, tiled 64x64x32, 4x4 microtile
// ---------------------------------------------------------------------------
#define BM 64
#define BN 64
#define BK 32

__global__ __launch_bounds__(256) void gemm_f32(
    const float* __restrict__ A, const float* __restrict__ B,
    float* __restrict__ C, int M, int K) {
  __shared__ __align__(16) float As[BK][BM + 4];
  __shared__ __align__(16) float Bs[BK][BN + 4];
  const int bm = blockIdx.x * BM;
  const int bn = blockIdx.y * BN;
  const int tid = threadIdx.x;
  const int tx = tid & 15;
  const int ty = tid >> 4;

  float acc[4][4] = {};

  const int arow = tid >> 2;        // 0..63 (A tile row)
  const int akq  = (tid & 3) * 8;   // k offset 0,8,16,24
  const int brow = tid >> 3;        // 0..31 (B tile k-row)
  const int bnq  = (tid & 7) * 8;   // n offset

  for (int bk = 0; bk < K; bk += BK) {
    // ---- load A tile (64 rows x 32 k), transposed into As[k][m]
    {
      const int gm = bm + arow;
      float4 v0, v1;
      if (gm < M) {
        const float* p = A + (size_t)gm * K + bk + akq;
        v0 = *(const float4*)p;
        v1 = *(const float4*)(p + 4);
      } else {
        v0 = make_float4(0.f, 0.f, 0.f, 0.f);
        v1 = v0;
      }
      As[akq + 0][arow] = v0.x; As[akq + 1][arow] = v0.y;
      As[akq + 2][arow] = v0.z; As[akq + 3][arow] = v0.w;
      As[akq + 4][arow] = v1.x; As[akq + 5][arow] = v1.y;
      As[akq + 6][arow] = v1.z; As[akq + 7][arow] = v1.w;
    }
    // ---- load B tile (32 k x 64 n)
    {
      const float* p = B + (size_t)(bk + brow) * HC + bn + bnq;
      float4 v0 = *(const float4*)p;
      float4 v1 = *(const float4*)(p + 4);
      *(float4*)&Bs[brow][bnq]     = v0;
      *(float4*)&Bs[brow][bnq + 4] = v1;
    }
    __syncthreads();
#pragma unroll
    for (int k = 0; k < BK; ++k) {
      float4 a4 = *(const float4*)&As[k][ty * 4];
      float4 b4 = *(const float4*)&Bs[k][tx * 4];
      float av[4] = {a4.x, a4.y, a4.z, a4.w};
      float bv[4] = {b4.x, b4.y, b4.z, b4.w};
#pragma unroll
      for (int i = 0; i < 4; ++i)
#pragma unroll
        for (int j = 0; j < 4; ++j)
          acc[i][j] = fmaf(av[i], bv[j], acc[i][j]);
    }
    __syncthreads();
  }
#pragma unroll
  for (int i = 0; i < 4; ++i) {
    int gm = bm + ty * 4 + i;
    if (gm < M) {
      float4 v = make_float4(acc[i][0], acc[i][1], acc[i][2], acc[i][3]);
      *(float4*)(C + (size_t)gm * HC + bn + tx * 4) = v;
    }
  }
}

// ---------------------------------------------------------------------------
// alpha: as[n,h] = sum_c h[n,h,c]*a_src[h,c]; ad likewise. Block = 1 node.
// ---------------------------------------------------------------------------
__global__ __launch_bounds__(256) void alpha_kernel(
    const float* __restrict__ h, const float* __restrict__ a_src,
    const float* __restrict__ a_dst, float* __restrict__ as_g,
    float* __restrict__ ad_g) {
  const int n = blockIdx.x;
  const int t = threadIdx.x;            // 256 = H*C channels
  float hv = h[(size_t)n * HC + t];
  float ps = hv * a_src[t];
  float pd = hv * a_dst[t];
#pragma unroll
  for (int off = 32; off > 0; off >>= 1) {
    ps += __shfl_down(ps, off);
    pd += __shfl_down(pd, off);
  }
  if ((t & 63) == 0) {
    int head = t >> 6;
    as_g[n * NHEAD + head] = ps;
    ad_g[n * NHEAD + head] = pd;
  }
}

// ---------------------------------------------------------------------------
// aggregate: per dst node, online-softmax over CSR in-edges, fused output.
// Block = 256 threads = 1 node; thread t owns (head = t>>6, channel = t&63).
// ---------------------------------------------------------------------------
__global__ __launch_bounds__(256) void aggregate_kernel(
    const float* __restrict__ h, const float* __restrict__ as_g,
    const float* __restrict__ ad_g, const int* __restrict__ row_ptr,
    const int* __restrict__ csr_src, const float* __restrict__ bias,
    float* __restrict__ out, int relu_flag) {
  const int n = blockIdx.x;
  const int t = threadIdx.x;
  const int head = t >> 6;
  const float ad = ad_g[n * NHEAD + head];
  const int beg = row_ptr[n];
  const int end = row_ptr[n + 1];

  float m = -1e30f, l = 0.f, acc = 0.f;
  for (int j = beg; j < end; ++j) {
    int src = csr_src[j];
    float e = as_g[src * NHEAD + head] + ad;
    e = (e >= 0.f) ? e : 0.2f * e;            // leaky_relu 0.2
    float mn = fmaxf(m, e);
    float sc = __expf(m - mn);
    float p  = __expf(e - mn);
    l = l * sc + p;
    acc = acc * sc + p * h[(size_t)src * HC + t];
    m = mn;
  }
  float o = acc / (l + 1e-16f) + bias[t];
  if (relu_flag) o = fmaxf(o, 0.f);
  out[(size_t)n * HC + t] = o;
}

// ---------------------------------------------------------------------------
// edge_index dtype sniffer: writes flag=1 if buffer is int64, 0 if int32.
// Values < 2^31, so int64 => every odd int32 word of first 256 pairs is 0.
// ---------------------------------------------------------------------------
__global__ void detect_kernel(const int* __restrict__ ei32, int* flag) {
  const int t = threadIdx.x;   // 64 threads
  int bad = 0;
#pragma unroll
  for (int r = 0; r < 4; ++r) {
    int i = r * 64 + t;
    if (ei32[2 * i + 1] != 0) bad = 1;
  }
#pragma unroll
  for (int off = 32; off > 0; off >>= 1) bad |= __shfl_down(bad, off);
  if (t == 0) *flag = bad ? 0 : 1;
}

__device__ inline void edge_pair(const int* __restrict__ ei32,
                                 const long long* __restrict__ ei64, int is64,
                                 int e, int E, int& src, int& dst) {
  if (e < E) {
    if (is64) { src = (int)ei64[e]; dst = (int)ei64[(size_t)E + e]; }
    else      { src = ei32[e];      dst = ei32[(size_t)E + e]; }
  } else {
    src = dst = e - E;   // self loops appended
  }
}

__global__ void count_kernel(const int* __restrict__ ei32, const int* __restrict__ flag,
                             int* __restrict__ cnt, int E, int Nn) {
  int e = blockIdx.x * blockDim.x + threadIdx.x;
  if (e >= E + Nn) return;
  int is64 = *flag;
  int src, dst;
  edge_pair(ei32, (const long long*)ei32, is64, e, E, src, dst);
  atomicAdd(&cnt[dst], 1);
}

__global__ void scatter_kernel(const int* __restrict__ ei32, const int* __restrict__ flag,
                               int* __restrict__ cursor, int* __restrict__ csr_src,
                               int E, int Nn) {
  int e = blockIdx.x * blockDim.x + threadIdx.x;
  if (e >= E + Nn) return;
  int is64 = *flag;
  int src, dst;
  edge_pair(ei32, (const long long*)ei32, is64, e, E, src, dst);
  int pos = atomicAdd(&cursor[dst], 1);
  csr_src[pos] = src;
}

// exclusive scan of cnt[0..Nn) into row_ptr[0..Nn], single block
__global__ __launch_bounds__(256) void scan_kernel(
    const int* __restrict__ cnt, int* __restrict__ row_ptr, int Nn) {
  __shared__ int swave[4];
  __shared__ int srun;
  const int t = threadIdx.x;
  const int lane = t & 63, w = t >> 6;
  if (t == 0) srun = 0;
  __syncthreads();
  for (int base = 0; base < Nn; base += 256) {
    int idx = base + t;
    int v = (idx < Nn) ? cnt[idx] : 0;
    int x = v;
#pragma unroll
    for (int off = 1; off < 64; off <<= 1) {
      int y = __shfl_up(x, off);
      if (lane >= off) x += y;
    }
    if (lane == 63) swave[w] = x;
    __syncthreads();
    int wofs = 0;
    for (int i = 0; i < w; ++i) wofs += swave[i];
    int run = srun;
    if (idx < Nn) row_ptr[idx] = run + wofs + x - v;   // exclusive
    __syncthreads();
    if (t == 0) srun = run + swave[0] + swave[1] + swave[2] + swave[3];
    __syncthreads();
  }
  if (t == 0) row_ptr[Nn] = srun;
}

__global__ void copy_int_kernel(const int* __restrict__ a, int* __restrict__ b, int n) {
  int i = blockIdx.x * blockDim.x + threadIdx.x;
  if (i < n) b[i] = a[i];
}

// ---------------------------------------------------------------------------
static inline size_t align_up(size_t v) { return (v + 255) & ~(size_t)255; }

extern "C" void kernel_launch(void* const* d_in, const int* in_sizes, int n_in,
                              void* d_out, int out_size, void* d_ws, size_t ws_size,
                              hipStream_t stream) {
  const float* x      = (const float*)d_in[0];
  const int*   ei32   = (const int*)d_in[1];
  const float* W1     = (const float*)d_in[2];
  const float* asrc1  = (const float*)d_in[3];
  const float* adst1  = (const float*)d_in[4];
  const float* b1     = (const float*)d_in[5];
  const float* W2     = (const float*)d_in[6];
  const float* asrc2  = (const float*)d_in[7];
  const float* adst2  = (const float*)d_in[8];
  const float* b2     = (const float*)d_in[9];
  const float* W3     = (const float*)d_in[10];
  const float* asrc3  = (const float*)d_in[11];
  const float* adst3  = (const float*)d_in[12];
  const float* b3     = (const float*)d_in[13];

  const int N = in_sizes[0] / 128;   // 50000
  const int E = in_sizes[1] / 2;     // 800000
  const int ET = E + N;              // with self loops
  float* out = (float*)d_out;

  // ---- workspace carve
  char* w = (char*)d_ws;
  float* H       = (float*)w; w += align_up((size_t)N * HC * sizeof(float));
  float* AS      = (float*)w; w += align_up((size_t)N * NHEAD * sizeof(float));
  float* AD      = (float*)w; w += align_up((size_t)N * NHEAD * sizeof(float));
  int*   cnt     = (int*)w;   w += align_up((size_t)N * sizeof(int));
  int*   row_ptr = (int*)w;   w += align_up((size_t)(N + 1) * sizeof(int));
  int*   cursor  = (int*)w;   w += align_up((size_t)(N + 1) * sizeof(int));
  int*   csr_src = (int*)w;   w += align_up((size_t)ET * sizeof(int));
  int*   flag    = (int*)w;   w += align_up(sizeof(int));

  // ---- CSR build (dst-grouped), once per call
  hipMemsetAsync(cnt, 0, (size_t)N * sizeof(int), stream);
  detect_kernel<<<1, 64, 0, stream>>>(ei32, flag);
  count_kernel<<<(ET + 255) / 256, 256, 0, stream>>>(ei32, flag, cnt, E, N);
  scan_kernel<<<1, 256, 0, stream>>>(cnt, row_ptr, N);
  copy_int_kernel<<<(N + 256) / 256, 256, 0, stream>>>(row_ptr, cursor, N + 1);
  scatter_kernel<<<(ET + 255) / 256, 256, 0, stream>>>(ei32, flag, cursor, csr_src, E, N);

  const dim3 gemm_grid((N + BM - 1) / BM, HC / BN);

  // ---- layer 1 (K=128), ReLU
  gemm_f32<<<gemm_grid, 256, 0, stream>>>(x, W1, H, N, 128);
  alpha_kernel<<<N, 256, 0, stream>>>(H, asrc1, adst1, AS, AD);
  aggregate_kernel<<<N, 256, 0, stream>>>(H, AS, AD, row_ptr, csr_src, b1, out, 1);

  // ---- layer 2 (K=256), ReLU
  gemm_f32<<<gemm_grid, 256, 0, stream>>>(out, W2, H, N, 256);
  alpha_kernel<<<N, 256, 0, stream>>>(H, asrc2, adst2, AS, AD);
  aggregate_kernel<<<N, 256, 0, stream>>>(H, AS, AD, row_ptr, csr_src, b2, out, 1);

  // ---- layer 3 (K=256), no ReLU
  gemm_f32<<<gemm_grid, 256, 0, stream>>>(out, W3, H, N, 256);
  alpha_kernel<<<N, 256, 0, stream>>>(H, asrc3, adst3, AS, AD);
  aggregate_kernel<<<N, 256, 0, stream>>>(H, AS, AD, row_ptr, csr_src, b3, out, 0);
}

// Round 2
// 960.792 us; speedup vs baseline: 1.1993x; 1.1993x over previous
//
#include <hip/hip_runtime.h>

#define HC 256      // H*C (all three layers output 256)
#define NHEAD 4

// ---------------------------------------------------------------------------
// GEMM: C[M,256] = A[M,K] @ B[K,256], f32, 128x128x32 tile, 8x8 microtile
// ---------------------------------------------------------------------------
#define BM 128
#define BN 128
#define BK 32

__global__ __launch_bounds__(256) void gemm_f32(
    const float* __restrict__ A, const float* __restrict__ B,
    float* __restrict__ C, int M, int K) {
  __shared__ float As[BK][BM + 4];   // k-major (transposed)
  __shared__ float Bs[BK][BN + 4];
  const int bm = blockIdx.x * BM;
  const int bn = blockIdx.y * BN;
  const int tid = threadIdx.x;
  const int wave = tid >> 6;
  const int lane = tid & 63;
  // 8x8 micro-tile position: wave quadrant + lane 8x8 grid
  const int mr = (wave & 1) * 8 + (lane & 7);    // 0..15, x8 rows
  const int nc = (wave >> 1) * 8 + (lane >> 3);  // 0..15, x8 cols

  // staging assignments
  const int arow = tid >> 1;          // 0..127
  const int akq  = (tid & 1) * 16;    // 0 or 16
  const int brow = tid >> 3;          // 0..31
  const int bcq  = (tid & 7) * 16;    // 0..112

  float acc[8][8] = {};

  for (int bk = 0; bk < K; bk += BK) {
    // global -> regs
    float4 av[4];
    const int gm = bm + arow;
    if (gm < M) {
      const float4* p = (const float4*)(A + (size_t)gm * K + bk + akq);
      av[0] = p[0]; av[1] = p[1]; av[2] = p[2]; av[3] = p[3];
    } else {
      av[0] = av[1] = av[2] = av[3] = make_float4(0.f, 0.f, 0.f, 0.f);
    }
    float4 bv[4];
    {
      const float4* q = (const float4*)(B + (size_t)(bk + brow) * HC + bn + bcq);
      bv[0] = q[0]; bv[1] = q[1]; bv[2] = q[2]; bv[3] = q[3];
    }
    __syncthreads();   // previous iter's LDS reads complete
    // regs -> LDS
#pragma unroll
    for (int u = 0; u < 4; ++u) {
      As[akq + 4 * u + 0][arow] = av[u].x;
      As[akq + 4 * u + 1][arow] = av[u].y;
      As[akq + 4 * u + 2][arow] = av[u].z;
      As[akq + 4 * u + 3][arow] = av[u].w;
    }
#pragma unroll
    for (int u = 0; u < 4; ++u)
      *(float4*)&Bs[brow][bcq + 4 * u] = bv[u];
    __syncthreads();
    // compute
#pragma unroll 8
    for (int k = 0; k < BK; ++k) {
      float4 a0 = *(const float4*)&As[k][mr * 8];
      float4 a1 = *(const float4*)&As[k][mr * 8 + 4];
      float4 b0 = *(const float4*)&Bs[k][nc * 8];
      float4 b1 = *(const float4*)&Bs[k][nc * 8 + 4];
      float a8[8] = {a0.x, a0.y, a0.z, a0.w, a1.x, a1.y, a1.z, a1.w};
      float b8[8] = {b0.x, b0.y, b0.z, b0.w, b1.x, b1.y, b1.z, b1.w};
#pragma unroll
      for (int i = 0; i < 8; ++i)
#pragma unroll
        for (int j = 0; j < 8; ++j)
          acc[i][j] = fmaf(a8[i], b8[j], acc[i][j]);
    }
  }
  // store
#pragma unroll
  for (int i = 0; i < 8; ++i) {
    const int row = bm + mr * 8 + i;
    if (row < M) {
      float4 v0 = make_float4(acc[i][0], acc[i][1], acc[i][2], acc[i][3]);
      float4 v1 = make_float4(acc[i][4], acc[i][5], acc[i][6], acc[i][7]);
      float4* c = (float4*)(C + (size_t)row * HC + bn + nc * 8);
      c[0] = v0; c[1] = v1;
    }
  }
}

// ---------------------------------------------------------------------------
// alpha: as[n,h] = sum_c h[n,h,c]*a_src[h,c]; ad likewise. Block = 1 node.
// ---------------------------------------------------------------------------
__global__ __launch_bounds__(256) void alpha_kernel(
    const float* __restrict__ h, const float* __restrict__ a_src,
    const float* __restrict__ a_dst, float* __restrict__ as_g,
    float* __restrict__ ad_g) {
  const int n = blockIdx.x;
  const int t = threadIdx.x;            // 256 = H*C channels
  float hv = h[(size_t)n * HC + t];
  float ps = hv * a_src[t];
  float pd = hv * a_dst[t];
#pragma unroll
  for (int off = 32; off > 0; off >>= 1) {
    ps += __shfl_down(ps, off);
    pd += __shfl_down(pd, off);
  }
  if ((t & 63) == 0) {
    int head = t >> 6;
    as_g[n * NHEAD + head] = ps;
    ad_g[n * NHEAD + head] = pd;
  }
}

// ---------------------------------------------------------------------------
// aggregate: 1 wave per dst node. Lane owns 4 channels (float4), head=lane>>4.
// Phase 1: lane-parallel max of as over in-edges (leaky monotone => exact m).
// Phase 2: single softmax pass, 4-edge chunked prefetch, no rescale chain.
// ---------------------------------------------------------------------------
__device__ __forceinline__ float comp4(float4 v, int i) {
  return (i == 0) ? v.x : (i == 1) ? v.y : (i == 2) ? v.z : v.w;
}

__global__ __launch_bounds__(256) void aggregate_kernel(
    const float* __restrict__ h, const float* __restrict__ as_g,
    const float* __restrict__ ad_g, const int* __restrict__ row_ptr,
    const int* __restrict__ csr_src, const float* __restrict__ bias,
    float* __restrict__ out, int relu_flag, int N) {
  const int wave = threadIdx.x >> 6;
  const int lane = threadIdx.x & 63;
  const int n = blockIdx.x * 4 + wave;
  if (n >= N) return;
  const int head = lane >> 4;
  const float4* __restrict__ h4 = (const float4*)h;
  const float4* __restrict__ as4 = (const float4*)as_g;

  const int beg = row_ptr[n];
  const int end = row_ptr[n + 1];

  // ---- phase 1: per-head max of as over in-edges
  float4 m4 = make_float4(-1e30f, -1e30f, -1e30f, -1e30f);
  for (int j = beg + lane; j < end; j += 64) {
    float4 a = as4[csr_src[j]];
    m4.x = fmaxf(m4.x, a.x); m4.y = fmaxf(m4.y, a.y);
    m4.z = fmaxf(m4.z, a.z); m4.w = fmaxf(m4.w, a.w);
  }
#pragma unroll
  for (int off = 32; off > 0; off >>= 1) {
    m4.x = fmaxf(m4.x, __shfl_xor(m4.x, off));
    m4.y = fmaxf(m4.y, __shfl_xor(m4.y, off));
    m4.z = fmaxf(m4.z, __shfl_xor(m4.z, off));
    m4.w = fmaxf(m4.w, __shfl_xor(m4.w, off));
  }
  const float ad = comp4(((const float4*)ad_g)[n], head);
  float mm = ad + comp4(m4, head);
  mm = (mm >= 0.f) ? mm : 0.2f * mm;     // exact segment max of e

  // ---- phase 2: single pass, chunked prefetch
  float l = 0.f;
  float4 acc = make_float4(0.f, 0.f, 0.f, 0.f);
  for (int j0 = beg; j0 < end; j0 += 4) {
    int s[4];
    float ae[4];
    float4 hv[4];
#pragma unroll
    for (int u = 0; u < 4; ++u) {
      int j = j0 + u;
      s[u] = csr_src[(j < end) ? j : (end - 1)];
    }
#pragma unroll
    for (int u = 0; u < 4; ++u) ae[u] = as_g[s[u] * NHEAD + head];
#pragma unroll
    for (int u = 0; u < 4; ++u) hv[u] = h4[(size_t)s[u] * 64 + lane];
#pragma unroll
    for (int u = 0; u < 4; ++u) {
      float e = ae[u] + ad;
      e = (e >= 0.f) ? e : 0.2f * e;
      float p = __expf(e - mm);
      p = (j0 + u < end) ? p : 0.f;
      l += p;
      acc.x = fmaf(p, hv[u].x, acc.x);
      acc.y = fmaf(p, hv[u].y, acc.y);
      acc.z = fmaf(p, hv[u].z, acc.z);
      acc.w = fmaf(p, hv[u].w, acc.w);
    }
  }
  const float inv = 1.f / (l + 1e-16f);
  float4 b4 = ((const float4*)bias)[lane];
  float4 o;
  o.x = acc.x * inv + b4.x; o.y = acc.y * inv + b4.y;
  o.z = acc.z * inv + b4.z; o.w = acc.w * inv + b4.w;
  if (relu_flag) {
    o.x = fmaxf(o.x, 0.f); o.y = fmaxf(o.y, 0.f);
    o.z = fmaxf(o.z, 0.f); o.w = fmaxf(o.w, 0.f);
  }
  ((float4*)out)[(size_t)n * 64 + lane] = o;
}

// ---------------------------------------------------------------------------
// edge_index dtype sniffer: flag=1 if int64 layout, 0 if int32.
// ---------------------------------------------------------------------------
__global__ void detect_kernel(const int* __restrict__ ei32, int* flag) {
  const int t = threadIdx.x;   // 64 threads
  int bad = 0;
#pragma unroll
  for (int r = 0; r < 4; ++r) {
    int i = r * 64 + t;
    if (ei32[2 * i + 1] != 0) bad = 1;
  }
#pragma unroll
  for (int off = 32; off > 0; off >>= 1) bad |= __shfl_down(bad, off);
  if (t == 0) *flag = bad ? 0 : 1;
}

__device__ inline void edge_pair(const int* __restrict__ ei32,
                                 const long long* __restrict__ ei64, int is64,
                                 int e, int E, int& src, int& dst) {
  if (e < E) {
    if (is64) { src = (int)ei64[e]; dst = (int)ei64[(size_t)E + e]; }
    else      { src = ei32[e];      dst = ei32[(size_t)E + e]; }
  } else {
    src = dst = e - E;   // self loops appended
  }
}

__global__ void count_kernel(const int* __restrict__ ei32, const int* __restrict__ flag,
                             int* __restrict__ cnt, int E, int Nn) {
  int e = blockIdx.x * blockDim.x + threadIdx.x;
  if (e >= E + Nn) return;
  int is64 = *flag;
  int src, dst;
  edge_pair(ei32, (const long long*)ei32, is64, e, E, src, dst);
  atomicAdd(&cnt[dst], 1);
}

__global__ void scatter_kernel(const int* __restrict__ ei32, const int* __restrict__ flag,
                               int* __restrict__ cursor, int* __restrict__ csr_src,
                               int E, int Nn) {
  int e = blockIdx.x * blockDim.x + threadIdx.x;
  if (e >= E + Nn) return;
  int is64 = *flag;
  int src, dst;
  edge_pair(ei32, (const long long*)ei32, is64, e, E, src, dst);
  int pos = atomicAdd(&cursor[dst], 1);
  csr_src[pos] = src;
}

// exclusive scan of cnt[0..Nn) into row_ptr[0..Nn], single block
__global__ __launch_bounds__(256) void scan_kernel(
    const int* __restrict__ cnt, int* __restrict__ row_ptr, int Nn) {
  __shared__ int swave[4];
  __shared__ int srun;
  const int t = threadIdx.x;
  const int lane = t & 63, w = t >> 6;
  if (t == 0) srun = 0;
  __syncthreads();
  for (int base = 0; base < Nn; base += 256) {
    int idx = base + t;
    int v = (idx < Nn) ? cnt[idx] : 0;
    int x = v;
#pragma unroll
    for (int off = 1; off < 64; off <<= 1) {
      int y = __shfl_up(x, off);
      if (lane >= off) x += y;
    }
    if (lane == 63) swave[w] = x;
    __syncthreads();
    int wofs = 0;
    for (int i = 0; i < w; ++i) wofs += swave[i];
    int run = srun;
    if (idx < Nn) row_ptr[idx] = run + wofs + x - v;   // exclusive
    __syncthreads();
    if (t == 0) srun = run + swave[0] + swave[1] + swave[2] + swave[3];
    __syncthreads();
  }
  if (t == 0) row_ptr[Nn] = srun;
}

__global__ void copy_int_kernel(const int* __restrict__ a, int* __restrict__ b, int n) {
  int i = blockIdx.x * blockDim.x + threadIdx.x;
  if (i < n) b[i] = a[i];
}

// ---------------------------------------------------------------------------
static inline size_t align_up(size_t v) { return (v + 255) & ~(size_t)255; }

extern "C" void kernel_launch(void* const* d_in, const int* in_sizes, int n_in,
                              void* d_out, int out_size, void* d_ws, size_t ws_size,
                              hipStream_t stream) {
  const float* x      = (const float*)d_in[0];
  const int*   ei32   = (const int*)d_in[1];
  const float* W1     = (const float*)d_in[2];
  const float* asrc1  = (const float*)d_in[3];
  const float* adst1  = (const float*)d_in[4];
  const float* b1     = (const float*)d_in[5];
  const float* W2     = (const float*)d_in[6];
  const float* asrc2  = (const float*)d_in[7];
  const float* adst2  = (const float*)d_in[8];
  const float* b2     = (const float*)d_in[9];
  const float* W3     = (const float*)d_in[10];
  const float* asrc3  = (const float*)d_in[11];
  const float* adst3  = (const float*)d_in[12];
  const float* b3     = (const float*)d_in[13];

  const int N = in_sizes[0] / 128;   // 50000
  const int E = in_sizes[1] / 2;     // 800000
  const int ET = E + N;              // with self loops
  float* out = (float*)d_out;

  // ---- workspace carve
  char* w = (char*)d_ws;
  float* H       = (float*)w; w += align_up((size_t)N * HC * sizeof(float));
  float* AS      = (float*)w; w += align_up((size_t)N * NHEAD * sizeof(float));
  float* AD      = (float*)w; w += align_up((size_t)N * NHEAD * sizeof(float));
  int*   cnt     = (int*)w;   w += align_up((size_t)N * sizeof(int));
  int*   row_ptr = (int*)w;   w += align_up((size_t)(N + 1) * sizeof(int));
  int*   cursor  = (int*)w;   w += align_up((size_t)(N + 1) * sizeof(int));
  int*   csr_src = (int*)w;   w += align_up((size_t)ET * sizeof(int));
  int*   flag    = (int*)w;   w += align_up(sizeof(int));

  // ---- CSR build (dst-grouped), once per call
  hipMemsetAsync(cnt, 0, (size_t)N * sizeof(int), stream);
  detect_kernel<<<1, 64, 0, stream>>>(ei32, flag);
  count_kernel<<<(ET + 255) / 256, 256, 0, stream>>>(ei32, flag, cnt, E, N);
  scan_kernel<<<1, 256, 0, stream>>>(cnt, row_ptr, N);
  copy_int_kernel<<<(N + 256) / 256, 256, 0, stream>>>(row_ptr, cursor, N + 1);
  scatter_kernel<<<(ET + 255) / 256, 256, 0, stream>>>(ei32, flag, cursor, csr_src, E, N);

  const dim3 gemm_grid((N + BM - 1) / BM, HC / BN);
  const int agg_grid = (N + 3) / 4;

  // ---- layer 1 (K=128), ReLU
  gemm_f32<<<gemm_grid, 256, 0, stream>>>(x, W1, H, N, 128);
  alpha_kernel<<<N, 256, 0, stream>>>(H, asrc1, adst1, AS, AD);
  aggregate_kernel<<<agg_grid, 256, 0, stream>>>(H, AS, AD, row_ptr, csr_src, b1, out, 1, N);

  // ---- layer 2 (K=256), ReLU
  gemm_f32<<<gemm_grid, 256, 0, stream>>>(out, W2, H, N, 256);
  alpha_kernel<<<N, 256, 0, stream>>>(H, asrc2, adst2, AS, AD);
  aggregate_kernel<<<agg_grid, 256, 0, stream>>>(H, AS, AD, row_ptr, csr_src, b2, out, 1, N);

  // ---- layer 3 (K=256), no ReLU
  gemm_f32<<<gemm_grid, 256, 0, stream>>>(out, W3, H, N, 256);
  alpha_kernel<<<N, 256, 0, stream>>>(H, asrc3, adst3, AS, AD);
  aggregate_kernel<<<agg_grid, 256, 0, stream>>>(H, AS, AD, row_ptr, csr_src, b3, out, 0, N);
}

// Round 3
// 777.387 us; speedup vs baseline: 1.4823x; 1.2359x over previous
//
#include <hip/hip_runtime.h>

#define HC 256      // H*C (all three layers output 256)
#define NHEAD 4

// ---------------------------------------------------------------------------
// GEMM: C[M,256] = A[M,K] @ B[K,256], f32, 128x128x32 tile, 8x8 microtile
// ---------------------------------------------------------------------------
#define BM 128
#define BN 128
#define BK 32

__global__ __launch_bounds__(256) void gemm_f32(
    const float* __restrict__ A, const float* __restrict__ B,
    float* __restrict__ C, int M, int K) {
  __shared__ float As[BK][BM + 4];   // k-major (transposed)
  __shared__ float Bs[BK][BN + 4];
  const int bm = blockIdx.x * BM;
  const int bn = blockIdx.y * BN;
  const int tid = threadIdx.x;
  const int wave = tid >> 6;
  const int lane = tid & 63;
  const int mr = (wave & 1) * 8 + (lane & 7);    // 0..15, x8 rows
  const int nc = (wave >> 1) * 8 + (lane >> 3);  // 0..15, x8 cols

  const int arow = tid >> 1;          // 0..127
  const int akq  = (tid & 1) * 16;    // 0 or 16
  const int brow = tid >> 3;          // 0..31
  const int bcq  = (tid & 7) * 16;    // 0..112

  float acc[8][8] = {};

  for (int bk = 0; bk < K; bk += BK) {
    float4 av[4];
    const int gm = bm + arow;
    if (gm < M) {
      const float4* p = (const float4*)(A + (size_t)gm * K + bk + akq);
      av[0] = p[0]; av[1] = p[1]; av[2] = p[2]; av[3] = p[3];
    } else {
      av[0] = av[1] = av[2] = av[3] = make_float4(0.f, 0.f, 0.f, 0.f);
    }
    float4 bv[4];
    {
      const float4* q = (const float4*)(B + (size_t)(bk + brow) * HC + bn + bcq);
      bv[0] = q[0]; bv[1] = q[1]; bv[2] = q[2]; bv[3] = q[3];
    }
    __syncthreads();
#pragma unroll
    for (int u = 0; u < 4; ++u) {
      As[akq + 4 * u + 0][arow] = av[u].x;
      As[akq + 4 * u + 1][arow] = av[u].y;
      As[akq + 4 * u + 2][arow] = av[u].z;
      As[akq + 4 * u + 3][arow] = av[u].w;
    }
#pragma unroll
    for (int u = 0; u < 4; ++u)
      *(float4*)&Bs[brow][bcq + 4 * u] = bv[u];
    __syncthreads();
#pragma unroll 8
    for (int k = 0; k < BK; ++k) {
      float4 a0 = *(const float4*)&As[k][mr * 8];
      float4 a1 = *(const float4*)&As[k][mr * 8 + 4];
      float4 b0 = *(const float4*)&Bs[k][nc * 8];
      float4 b1 = *(const float4*)&Bs[k][nc * 8 + 4];
      float a8[8] = {a0.x, a0.y, a0.z, a0.w, a1.x, a1.y, a1.z, a1.w};
      float b8[8] = {b0.x, b0.y, b0.z, b0.w, b1.x, b1.y, b1.z, b1.w};
#pragma unroll
      for (int i = 0; i < 8; ++i)
#pragma unroll
        for (int j = 0; j < 8; ++j)
          acc[i][j] = fmaf(a8[i], b8[j], acc[i][j]);
    }
  }
#pragma unroll
  for (int i = 0; i < 8; ++i) {
    const int row = bm + mr * 8 + i;
    if (row < M) {
      float4 v0 = make_float4(acc[i][0], acc[i][1], acc[i][2], acc[i][3]);
      float4 v1 = make_float4(acc[i][4], acc[i][5], acc[i][6], acc[i][7]);
      float4* c = (float4*)(C + (size_t)row * HC + bn + nc * 8);
      c[0] = v0; c[1] = v1;
    }
  }
}

// ---------------------------------------------------------------------------
// alpha: as[n,h] = sum_c h[n,h,c]*a_src[h,c]; ad likewise.
// 1 wave per node, lane owns float4 (16B coalesced); head = lane>>4.
// ---------------------------------------------------------------------------
__global__ __launch_bounds__(256) void alpha_kernel(
    const float* __restrict__ h, const float* __restrict__ a_src,
    const float* __restrict__ a_dst, float* __restrict__ as_g,
    float* __restrict__ ad_g, int N) {
  const int wave = threadIdx.x >> 6;
  const int lane = threadIdx.x & 63;
  const int n = blockIdx.x * 4 + wave;
  if (n >= N) return;
  float4 hv = ((const float4*)h)[(size_t)n * 64 + lane];
  float4 s4 = ((const float4*)a_src)[lane];
  float4 d4 = ((const float4*)a_dst)[lane];
  float ps = hv.x * s4.x + hv.y * s4.y + hv.z * s4.z + hv.w * s4.w;
  float pd = hv.x * d4.x + hv.y * d4.y + hv.z * d4.z + hv.w * d4.w;
#pragma unroll
  for (int off = 1; off < 16; off <<= 1) {
    ps += __shfl_xor(ps, off);
    pd += __shfl_xor(pd, off);
  }
  if ((lane & 15) == 0) {
    int head = lane >> 4;
    as_g[n * NHEAD + head] = ps;
    ad_g[n * NHEAD + head] = pd;
  }
}

// ---------------------------------------------------------------------------
// aggregate: 1 wave per dst node. Lane owns 4 channels (float4), head=lane>>4.
// Phase 1: lane-parallel max of as over in-edges (leaky monotone => exact m).
// Phase 2: single softmax pass, 4-edge chunked prefetch, no rescale chain.
// ---------------------------------------------------------------------------
__device__ __forceinline__ float comp4(float4 v, int i) {
  return (i == 0) ? v.x : (i == 1) ? v.y : (i == 2) ? v.z : v.w;
}

__global__ __launch_bounds__(256) void aggregate_kernel(
    const float* __restrict__ h, const float* __restrict__ as_g,
    const float* __restrict__ ad_g, const int* __restrict__ row_ptr,
    const int* __restrict__ csr_src, const float* __restrict__ bias,
    float* __restrict__ out, int relu_flag, int N) {
  const int wave = threadIdx.x >> 6;
  const int lane = threadIdx.x & 63;
  const int n = blockIdx.x * 4 + wave;
  if (n >= N) return;
  const int head = lane >> 4;
  const float4* __restrict__ h4 = (const float4*)h;
  const float4* __restrict__ as4 = (const float4*)as_g;

  const int beg = row_ptr[n];
  const int end = row_ptr[n + 1];

  // ---- phase 1: per-head max of as over in-edges
  float4 m4 = make_float4(-1e30f, -1e30f, -1e30f, -1e30f);
  for (int j = beg + lane; j < end; j += 64) {
    float4 a = as4[csr_src[j]];
    m4.x = fmaxf(m4.x, a.x); m4.y = fmaxf(m4.y, a.y);
    m4.z = fmaxf(m4.z, a.z); m4.w = fmaxf(m4.w, a.w);
  }
#pragma unroll
  for (int off = 32; off > 0; off >>= 1) {
    m4.x = fmaxf(m4.x, __shfl_xor(m4.x, off));
    m4.y = fmaxf(m4.y, __shfl_xor(m4.y, off));
    m4.z = fmaxf(m4.z, __shfl_xor(m4.z, off));
    m4.w = fmaxf(m4.w, __shfl_xor(m4.w, off));
  }
  const float ad = comp4(((const float4*)ad_g)[n], head);
  float mm = ad + comp4(m4, head);
  mm = (mm >= 0.f) ? mm : 0.2f * mm;     // exact segment max of e

  // ---- phase 2: single pass, chunked prefetch
  float l = 0.f;
  float4 acc = make_float4(0.f, 0.f, 0.f, 0.f);
  for (int j0 = beg; j0 < end; j0 += 4) {
    int s[4];
    float ae[4];
    float4 hv[4];
#pragma unroll
    for (int u = 0; u < 4; ++u) {
      int j = j0 + u;
      s[u] = csr_src[(j < end) ? j : (end - 1)];
    }
#pragma unroll
    for (int u = 0; u < 4; ++u) ae[u] = as_g[s[u] * NHEAD + head];
#pragma unroll
    for (int u = 0; u < 4; ++u) hv[u] = h4[(size_t)s[u] * 64 + lane];
#pragma unroll
    for (int u = 0; u < 4; ++u) {
      float e = ae[u] + ad;
      e = (e >= 0.f) ? e : 0.2f * e;
      float p = __expf(e - mm);
      p = (j0 + u < end) ? p : 0.f;
      l += p;
      acc.x = fmaf(p, hv[u].x, acc.x);
      acc.y = fmaf(p, hv[u].y, acc.y);
      acc.z = fmaf(p, hv[u].z, acc.z);
      acc.w = fmaf(p, hv[u].w, acc.w);
    }
  }
  const float inv = 1.f / (l + 1e-16f);
  float4 b4 = ((const float4*)bias)[lane];
  float4 o;
  o.x = acc.x * inv + b4.x; o.y = acc.y * inv + b4.y;
  o.z = acc.z * inv + b4.z; o.w = acc.w * inv + b4.w;
  if (relu_flag) {
    o.x = fmaxf(o.x, 0.f); o.y = fmaxf(o.y, 0.f);
    o.z = fmaxf(o.z, 0.f); o.w = fmaxf(o.w, 0.f);
  }
  ((float4*)out)[(size_t)n * 64 + lane] = o;
}

// ---------------------------------------------------------------------------
// edge_index dtype sniffer: flag=1 if int64 layout, 0 if int32.
// ---------------------------------------------------------------------------
__global__ void detect_kernel(const int* __restrict__ ei32, int* flag) {
  const int t = threadIdx.x;   // 64 threads
  int bad = 0;
#pragma unroll
  for (int r = 0; r < 4; ++r) {
    int i = r * 64 + t;
    if (ei32[2 * i + 1] != 0) bad = 1;
  }
#pragma unroll
  for (int off = 32; off > 0; off >>= 1) bad |= __shfl_down(bad, off);
  if (t == 0) *flag = bad ? 0 : 1;
}

__device__ inline void edge_pair(const int* __restrict__ ei32,
                                 const long long* __restrict__ ei64, int is64,
                                 int e, int E, int& src, int& dst) {
  if (e < E) {
    if (is64) { src = (int)ei64[e]; dst = (int)ei64[(size_t)E + e]; }
    else      { src = ei32[e];      dst = ei32[(size_t)E + e]; }
  } else {
    src = dst = e - E;   // self loops appended
  }
}

__global__ void count_kernel(const int* __restrict__ ei32, const int* __restrict__ flag,
                             int* __restrict__ cnt, int E, int Nn) {
  int e = blockIdx.x * blockDim.x + threadIdx.x;
  if (e >= E + Nn) return;
  int is64 = *flag;
  int src, dst;
  edge_pair(ei32, (const long long*)ei32, is64, e, E, src, dst);
  atomicAdd(&cnt[dst], 1);
}

__global__ void scatter_kernel(const int* __restrict__ ei32, const int* __restrict__ flag,
                               int* __restrict__ cursor, int* __restrict__ csr_src,
                               int E, int Nn) {
  int e = blockIdx.x * blockDim.x + threadIdx.x;
  if (e >= E + Nn) return;
  int is64 = *flag;
  int src, dst;
  edge_pair(ei32, (const long long*)ei32, is64, e, E, src, dst);
  int pos = atomicAdd(&cursor[dst], 1);
  csr_src[pos] = src;
}

// ---------------------------------------------------------------------------
// hierarchical exclusive scan: blocks -> partials -> add offsets
// ---------------------------------------------------------------------------
__global__ __launch_bounds__(256) void scan_blocks(
    const int* __restrict__ cnt, int* __restrict__ local,
    int* __restrict__ partials, int Nn) {
  __shared__ int swave[4];
  const int t = threadIdx.x, lane = t & 63, w = t >> 6;
  const int idx = blockIdx.x * 256 + t;
  int v = (idx < Nn) ? cnt[idx] : 0;
  int x = v;
#pragma unroll
  for (int off = 1; off < 64; off <<= 1) {
    int y = __shfl_up(x, off);
    if (lane >= off) x += y;
  }
  if (lane == 63) swave[w] = x;
  __syncthreads();
  int wofs = 0;
#pragma unroll
  for (int i = 0; i < 3; ++i) wofs += (i < w) ? swave[i] : 0;
  if (idx < Nn) local[idx] = wofs + x - v;          // block-local exclusive
  if (t == 255) partials[blockIdx.x] = wofs + x;    // block total
}

// single block; nb <= 256
__global__ __launch_bounds__(256) void scan_partials(
    int* __restrict__ partials, int nb, int* __restrict__ total_out) {
  __shared__ int swave[4];
  const int t = threadIdx.x, lane = t & 63, w = t >> 6;
  int v = (t < nb) ? partials[t] : 0;
  int x = v;
#pragma unroll
  for (int off = 1; off < 64; off <<= 1) {
    int y = __shfl_up(x, off);
    if (lane >= off) x += y;
  }
  if (lane == 63) swave[w] = x;
  __syncthreads();
  int wofs = 0;
#pragma unroll
  for (int i = 0; i < 3; ++i) wofs += (i < w) ? swave[i] : 0;
  int excl = wofs + x - v;
  if (t < nb) partials[t] = excl;
  if (t == nb - 1) *total_out = excl + v;           // row_ptr[N] = grand total
}

__global__ void add_offsets(const int* __restrict__ local,
                            const int* __restrict__ partials,
                            int* __restrict__ row_ptr, int* __restrict__ cursor,
                            int Nn) {
  const int idx = blockIdx.x * 256 + threadIdx.x;
  if (idx < Nn) {
    int v = local[idx] + partials[blockIdx.x];
    row_ptr[idx] = v;
    cursor[idx] = v;
  }
}

// ---------------------------------------------------------------------------
static inline size_t align_up(size_t v) { return (v + 255) & ~(size_t)255; }

extern "C" void kernel_launch(void* const* d_in, const int* in_sizes, int n_in,
                              void* d_out, int out_size, void* d_ws, size_t ws_size,
                              hipStream_t stream) {
  const float* x      = (const float*)d_in[0];
  const int*   ei32   = (const int*)d_in[1];
  const float* W1     = (const float*)d_in[2];
  const float* asrc1  = (const float*)d_in[3];
  const float* adst1  = (const float*)d_in[4];
  const float* b1     = (const float*)d_in[5];
  const float* W2     = (const float*)d_in[6];
  const float* asrc2  = (const float*)d_in[7];
  const float* adst2  = (const float*)d_in[8];
  const float* b2     = (const float*)d_in[9];
  const float* W3     = (const float*)d_in[10];
  const float* asrc3  = (const float*)d_in[11];
  const float* adst3  = (const float*)d_in[12];
  const float* b3     = (const float*)d_in[13];

  const int N = in_sizes[0] / 128;   // 50000
  const int E = in_sizes[1] / 2;     // 800000
  const int ET = E + N;              // with self loops
  float* out = (float*)d_out;
  const int nb = (N + 255) / 256;    // scan blocks (196 <= 256)

  // ---- workspace carve
  char* w = (char*)d_ws;
  float* H       = (float*)w; w += align_up((size_t)N * HC * sizeof(float));
  float* AS      = (float*)w; w += align_up((size_t)N * NHEAD * sizeof(float));
  float* AD      = (float*)w; w += align_up((size_t)N * NHEAD * sizeof(float));
  int*   cnt     = (int*)w;   w += align_up((size_t)N * sizeof(int));
  int*   local   = (int*)w;   w += align_up((size_t)N * sizeof(int));
  int*   row_ptr = (int*)w;   w += align_up((size_t)(N + 1) * sizeof(int));
  int*   cursor  = (int*)w;   w += align_up((size_t)(N + 1) * sizeof(int));
  int*   parts   = (int*)w;   w += align_up(256 * sizeof(int));
  int*   csr_src = (int*)w;   w += align_up((size_t)ET * sizeof(int));
  int*   flag    = (int*)w;   w += align_up(sizeof(int));

  // ---- CSR build (dst-grouped), once per call
  hipMemsetAsync(cnt, 0, (size_t)N * sizeof(int), stream);
  detect_kernel<<<1, 64, 0, stream>>>(ei32, flag);
  count_kernel<<<(ET + 255) / 256, 256, 0, stream>>>(ei32, flag, cnt, E, N);
  scan_blocks<<<nb, 256, 0, stream>>>(cnt, local, parts, N);
  scan_partials<<<1, 256, 0, stream>>>(parts, nb, row_ptr + N);
  add_offsets<<<nb, 256, 0, stream>>>(local, parts, row_ptr, cursor, N);
  scatter_kernel<<<(ET + 255) / 256, 256, 0, stream>>>(ei32, flag, cursor, csr_src, E, N);

  const dim3 gemm_grid((N + BM - 1) / BM, HC / BN);
  const int ablk = (N + 3) / 4;

  // ---- layer 1 (K=128), ReLU
  gemm_f32<<<gemm_grid, 256, 0, stream>>>(x, W1, H, N, 128);
  alpha_kernel<<<ablk, 256, 0, stream>>>(H, asrc1, adst1, AS, AD, N);
  aggregate_kernel<<<ablk, 256, 0, stream>>>(H, AS, AD, row_ptr, csr_src, b1, out, 1, N);

  // ---- layer 2 (K=256), ReLU
  gemm_f32<<<gemm_grid, 256, 0, stream>>>(out, W2, H, N, 256);
  alpha_kernel<<<ablk, 256, 0, stream>>>(H, asrc2, adst2, AS, AD, N);
  aggregate_kernel<<<ablk, 256, 0, stream>>>(H, AS, AD, row_ptr, csr_src, b2, out, 1, N);

  // ---- layer 3 (K=256), no ReLU
  gemm_f32<<<gemm_grid, 256, 0, stream>>>(out, W3, H, N, 256);
  alpha_kernel<<<ablk, 256, 0, stream>>>(H, asrc3, adst3, AS, AD, N);
  aggregate_kernel<<<ablk, 256, 0, stream>>>(H, AS, AD, row_ptr, csr_src, b3, out, 0, N);
}

// Round 4
// 611.774 us; speedup vs baseline: 1.8835x; 1.2707x over previous
//
#include <hip/hip_runtime.h>
#include <hip/hip_bf16.h>

typedef unsigned short u16;
typedef __attribute__((ext_vector_type(8))) short short8;
typedef __attribute__((ext_vector_type(4))) float f32x4;

#define HC 256      // H*C (all three layers output 256)
#define NHEAD 4

// ---------------------------------------------------------------------------
// bf16 helpers: truncation split (hi = top 16 bits, lo = rne(v - hi))
// pair error ~2^-17 |v|; dropped lo*lo term ~2^-16 |ab|.
// ---------------------------------------------------------------------------
__device__ __forceinline__ u16 f2b_rne(float v) {
  __hip_bfloat16 b = __float2bfloat16(v);
  union { __hip_bfloat16 b; u16 u; } cv; cv.b = b; return cv.u;
}

// ---------------------------------------------------------------------------
// W convert: Wth/Wtl[n*K + k] = split_bf16(W[k*256 + n])  (transposed, k-major)
// ---------------------------------------------------------------------------
__global__ void convert_w(const float* __restrict__ W, u16* __restrict__ Wth,
                          u16* __restrict__ Wtl, int K) {
  int id = blockIdx.x * 256 + threadIdx.x;
  if (id >= K * 256) return;
  int k = id >> 8, n = id & 255;
  float v = W[id];
  unsigned bits = __float_as_uint(v);
  u16 hi = (u16)(bits >> 16);
  float hf = __uint_as_float((unsigned)hi << 16);
  u16 lo = f2b_rne(v - hf);
  Wth[n * K + k] = hi;
  Wtl[n * K + k] = lo;
}

// ---------------------------------------------------------------------------
// GEMM: C[M,256] = A[M,K] @ B[K,256] via split-bf16 MFMA 16x16x32.
// Block 128x128x64, 4 waves 2x2, wave tile 64x64 (4x4 frags).
// A (f32) split on the fly during staging; B pre-split/transposed [256][K].
// LDS [row][k] XOR-swizzled: idx ^= (row&7)<<3 (units of ushort).
// Swapped mfma operands => acc lane layout: row=lane&15, col=(lane>>4)*4+reg.
// ---------------------------------------------------------------------------
#define GBM 128
#define GBN 128
#define GBK 64

__global__ __launch_bounds__(256, 2) void gemm_mfma(
    const float* __restrict__ A, const u16* __restrict__ Bth,
    const u16* __restrict__ Btl, float* __restrict__ C, int M, int K) {
  __shared__ u16 AH[128 * 64], AL[128 * 64], BH[128 * 64], BL[128 * 64];
  const int tid = threadIdx.x;
  const int lane = tid & 63;
  const int wave = tid >> 6;
  const int wm = (wave & 1) * 64;
  const int wn = (wave >> 1) * 64;
  const int bm = blockIdx.x * GBM;
  const int bn = blockIdx.y * GBN;

  const int srow = tid >> 1;          // staging row 0..127
  const int skh  = (tid & 1) * 32;    // k half 0/32

  f32x4 acc[4][4] = {};

  const int agm = (bm + srow < M) ? (bm + srow) : (M - 1);

  for (int bk = 0; bk < K; bk += GBK) {
    // ---- global loads
    float4 a0[4], a1[4];
    const float* arow = A + (size_t)agm * K + bk + skh;
#pragma unroll
    for (int u = 0; u < 4; ++u) {
      a0[u] = ((const float4*)arow)[2 * u];
      a1[u] = ((const float4*)arow)[2 * u + 1];
    }
    short8 sbh[4], sbl[4];
    const u16* bhrow = Bth + (size_t)(bn + srow) * K + bk + skh;
    const u16* blrow = Btl + (size_t)(bn + srow) * K + bk + skh;
#pragma unroll
    for (int u = 0; u < 4; ++u) {
      sbh[u] = *(const short8*)(bhrow + 8 * u);
      sbl[u] = *(const short8*)(blrow + 8 * u);
    }
    __syncthreads();   // previous compute done reading LDS
    // ---- convert + LDS writes (swizzled)
#pragma unroll
    for (int u = 0; u < 4; ++u) {
      int idx = (srow * 64 + skh + u * 8) ^ ((srow & 7) << 3);
      float va[8] = {a0[u].x, a0[u].y, a0[u].z, a0[u].w,
                     a1[u].x, a1[u].y, a1[u].z, a1[u].w};
      short8 hi, lo;
#pragma unroll
      for (int j = 0; j < 8; ++j) {
        unsigned bits = __float_as_uint(va[j]);
        u16 h = (u16)(bits >> 16);
        float hf = __uint_as_float((unsigned)h << 16);
        u16 l = f2b_rne(va[j] - hf);
        ((short*)&hi)[j] = (short)h;
        ((short*)&lo)[j] = (short)l;
      }
      *(short8*)&AH[idx] = hi;
      *(short8*)&AL[idx] = lo;
      *(short8*)&BH[idx] = sbh[u];
      *(short8*)&BL[idx] = sbl[u];
    }
    __syncthreads();
    // ---- compute: 2 k-steps of 32
#pragma unroll
    for (int ks = 0; ks < 2; ++ks) {
      const int k0 = ks * 32 + (lane >> 4) * 8;
      short8 fah[4], fal[4], fbh[4], fbl[4];
#pragma unroll
      for (int mt = 0; mt < 4; ++mt) {
        int r = wm + mt * 16 + (lane & 15);
        int idx = (r * 64 + k0) ^ ((r & 7) << 3);
        fah[mt] = *(const short8*)&AH[idx];
        fal[mt] = *(const short8*)&AL[idx];
      }
#pragma unroll
      for (int nt = 0; nt < 4; ++nt) {
        int r = wn + nt * 16 + (lane & 15);
        int idx = (r * 64 + k0) ^ ((r & 7) << 3);
        fbh[nt] = *(const short8*)&BH[idx];
        fbl[nt] = *(const short8*)&BL[idx];
      }
#pragma unroll
      for (int mt = 0; mt < 4; ++mt)
#pragma unroll
        for (int nt = 0; nt < 4; ++nt) {
          acc[mt][nt] = __builtin_amdgcn_mfma_f32_16x16x32_bf16(
              fbh[nt], fah[mt], acc[mt][nt], 0, 0, 0);
          acc[mt][nt] = __builtin_amdgcn_mfma_f32_16x16x32_bf16(
              fbh[nt], fal[mt], acc[mt][nt], 0, 0, 0);
          acc[mt][nt] = __builtin_amdgcn_mfma_f32_16x16x32_bf16(
              fbl[nt], fah[mt], acc[mt][nt], 0, 0, 0);
        }
    }
  }
  // ---- store: row = bm+wm+mt*16+(lane&15); col base = bn+wn+(lane>>4)*4
#pragma unroll
  for (int mt = 0; mt < 4; ++mt) {
    int row = bm + wm + mt * 16 + (lane & 15);
    if (row < M) {
      float* cp = C + (size_t)row * HC + bn + wn + (lane >> 4) * 4;
#pragma unroll
      for (int nt = 0; nt < 4; ++nt)
        *(f32x4*)(cp + nt * 16) = acc[mt][nt];
    }
  }
}

// ---------------------------------------------------------------------------
// alpha: as[n,h] = sum_c h[n,h,c]*a_src[h,c]; ad likewise.
// 1 wave per node, lane owns float4; head = lane>>4.
// ---------------------------------------------------------------------------
__global__ __launch_bounds__(256) void alpha_kernel(
    const float* __restrict__ h, const float* __restrict__ a_src,
    const float* __restrict__ a_dst, float* __restrict__ as_g,
    float* __restrict__ ad_g, int N) {
  const int wave = threadIdx.x >> 6;
  const int lane = threadIdx.x & 63;
  const int n = blockIdx.x * 4 + wave;
  if (n >= N) return;
  float4 hv = ((const float4*)h)[(size_t)n * 64 + lane];
  float4 s4 = ((const float4*)a_src)[lane];
  float4 d4 = ((const float4*)a_dst)[lane];
  float ps = hv.x * s4.x + hv.y * s4.y + hv.z * s4.z + hv.w * s4.w;
  float pd = hv.x * d4.x + hv.y * d4.y + hv.z * d4.z + hv.w * d4.w;
#pragma unroll
  for (int off = 1; off < 16; off <<= 1) {
    ps += __shfl_xor(ps, off);
    pd += __shfl_xor(pd, off);
  }
  if ((lane & 15) == 0) {
    int head = lane >> 4;
    as_g[n * NHEAD + head] = ps;
    ad_g[n * NHEAD + head] = pd;
  }
}

// ---------------------------------------------------------------------------
// aggregate: 1 wave per dst node, 8-deep chunked prefetch.
// ---------------------------------------------------------------------------
__device__ __forceinline__ float comp4(float4 v, int i) {
  return (i == 0) ? v.x : (i == 1) ? v.y : (i == 2) ? v.z : v.w;
}

__global__ __launch_bounds__(256) void aggregate_kernel(
    const float* __restrict__ h, const float* __restrict__ as_g,
    const float* __restrict__ ad_g, const int* __restrict__ row_ptr,
    const int* __restrict__ csr_src, const float* __restrict__ bias,
    float* __restrict__ out, int relu_flag, int N) {
  const int wave = threadIdx.x >> 6;
  const int lane = threadIdx.x & 63;
  const int n = blockIdx.x * 4 + wave;
  if (n >= N) return;
  const int head = lane >> 4;
  const float4* __restrict__ h4 = (const float4*)h;
  const float4* __restrict__ as4 = (const float4*)as_g;

  const int beg = row_ptr[n];
  const int end = row_ptr[n + 1];

  // ---- phase 1: per-head max of as over in-edges
  float4 m4 = make_float4(-1e30f, -1e30f, -1e30f, -1e30f);
  for (int j = beg + lane; j < end; j += 64) {
    float4 a = as4[csr_src[j]];
    m4.x = fmaxf(m4.x, a.x); m4.y = fmaxf(m4.y, a.y);
    m4.z = fmaxf(m4.z, a.z); m4.w = fmaxf(m4.w, a.w);
  }
#pragma unroll
  for (int off = 32; off > 0; off >>= 1) {
    m4.x = fmaxf(m4.x, __shfl_xor(m4.x, off));
    m4.y = fmaxf(m4.y, __shfl_xor(m4.y, off));
    m4.z = fmaxf(m4.z, __shfl_xor(m4.z, off));
    m4.w = fmaxf(m4.w, __shfl_xor(m4.w, off));
  }
  const float ad = comp4(((const float4*)ad_g)[n], head);
  float mm = ad + comp4(m4, head);
  mm = (mm >= 0.f) ? mm : 0.2f * mm;     // exact segment max of e

  // ---- phase 2: single pass, 8-deep chunked prefetch
  float l = 0.f;
  float4 acc = make_float4(0.f, 0.f, 0.f, 0.f);
  for (int j0 = beg; j0 < end; j0 += 8) {
    int s[8];
    float ae[8];
    float4 hv[8];
#pragma unroll
    for (int u = 0; u < 8; ++u) {
      int j = j0 + u;
      s[u] = csr_src[(j < end) ? j : (end - 1)];
    }
#pragma unroll
    for (int u = 0; u < 8; ++u) ae[u] = as_g[s[u] * NHEAD + head];
#pragma unroll
    for (int u = 0; u < 8; ++u) hv[u] = h4[(size_t)s[u] * 64 + lane];
#pragma unroll
    for (int u = 0; u < 8; ++u) {
      float e = ae[u] + ad;
      e = (e >= 0.f) ? e : 0.2f * e;
      float p = __expf(e - mm);
      p = (j0 + u < end) ? p : 0.f;
      l += p;
      acc.x = fmaf(p, hv[u].x, acc.x);
      acc.y = fmaf(p, hv[u].y, acc.y);
      acc.z = fmaf(p, hv[u].z, acc.z);
      acc.w = fmaf(p, hv[u].w, acc.w);
    }
  }
  const float inv = 1.f / (l + 1e-16f);
  float4 b4 = ((const float4*)bias)[lane];
  float4 o;
  o.x = acc.x * inv + b4.x; o.y = acc.y * inv + b4.y;
  o.z = acc.z * inv + b4.z; o.w = acc.w * inv + b4.w;
  if (relu_flag) {
    o.x = fmaxf(o.x, 0.f); o.y = fmaxf(o.y, 0.f);
    o.z = fmaxf(o.z, 0.f); o.w = fmaxf(o.w, 0.f);
  }
  ((float4*)out)[(size_t)n * 64 + lane] = o;
}

// ---------------------------------------------------------------------------
// edge_index dtype sniffer: flag=1 if int64 layout, 0 if int32.
// ---------------------------------------------------------------------------
__global__ void detect_kernel(const int* __restrict__ ei32, int* flag) {
  const int t = threadIdx.x;   // 64 threads
  int bad = 0;
#pragma unroll
  for (int r = 0; r < 4; ++r) {
    int i = r * 64 + t;
    if (ei32[2 * i + 1] != 0) bad = 1;
  }
#pragma unroll
  for (int off = 32; off > 0; off >>= 1) bad |= __shfl_down(bad, off);
  if (t == 0) *flag = bad ? 0 : 1;
}

__device__ inline void edge_pair(const int* __restrict__ ei32,
                                 const long long* __restrict__ ei64, int is64,
                                 int e, int E, int& src, int& dst) {
  if (e < E) {
    if (is64) { src = (int)ei64[e]; dst = (int)ei64[(size_t)E + e]; }
    else      { src = ei32[e];      dst = ei32[(size_t)E + e]; }
  } else {
    src = dst = e - E;   // self loops appended
  }
}

__global__ void count_kernel(const int* __restrict__ ei32, const int* __restrict__ flag,
                             int* __restrict__ cnt, int E, int Nn) {
  int e = blockIdx.x * blockDim.x + threadIdx.x;
  if (e >= E + Nn) return;
  int is64 = *flag;
  int src, dst;
  edge_pair(ei32, (const long long*)ei32, is64, e, E, src, dst);
  atomicAdd(&cnt[dst], 1);
}

__global__ void scatter_kernel(const int* __restrict__ ei32, const int* __restrict__ flag,
                               int* __restrict__ cursor, int* __restrict__ csr_src,
                               int E, int Nn) {
  int e = blockIdx.x * blockDim.x + threadIdx.x;
  if (e >= E + Nn) return;
  int is64 = *flag;
  int src, dst;
  edge_pair(ei32, (const long long*)ei32, is64, e, E, src, dst);
  int pos = atomicAdd(&cursor[dst], 1);
  csr_src[pos] = src;
}

// ---------------------------------------------------------------------------
// hierarchical exclusive scan: blocks -> partials -> add offsets
// ---------------------------------------------------------------------------
__global__ __launch_bounds__(256) void scan_blocks(
    const int* __restrict__ cnt, int* __restrict__ local,
    int* __restrict__ partials, int Nn) {
  __shared__ int swave[4];
  const int t = threadIdx.x, lane = t & 63, w = t >> 6;
  const int idx = blockIdx.x * 256 + t;
  int v = (idx < Nn) ? cnt[idx] : 0;
  int x = v;
#pragma unroll
  for (int off = 1; off < 64; off <<= 1) {
    int y = __shfl_up(x, off);
    if (lane >= off) x += y;
  }
  if (lane == 63) swave[w] = x;
  __syncthreads();
  int wofs = 0;
#pragma unroll
  for (int i = 0; i < 3; ++i) wofs += (i < w) ? swave[i] : 0;
  if (idx < Nn) local[idx] = wofs + x - v;          // block-local exclusive
  if (t == 255) partials[blockIdx.x] = wofs + x;    // block total
}

__global__ __launch_bounds__(256) void scan_partials(
    int* __restrict__ partials, int nb, int* __restrict__ total_out) {
  __shared__ int swave[4];
  const int t = threadIdx.x, lane = t & 63, w = t >> 6;
  int v = (t < nb) ? partials[t] : 0;
  int x = v;
#pragma unroll
  for (int off = 1; off < 64; off <<= 1) {
    int y = __shfl_up(x, off);
    if (lane >= off) x += y;
  }
  if (lane == 63) swave[w] = x;
  __syncthreads();
  int wofs = 0;
#pragma unroll
  for (int i = 0; i < 3; ++i) wofs += (i < w) ? swave[i] : 0;
  int excl = wofs + x - v;
  if (t < nb) partials[t] = excl;
  if (t == nb - 1) *total_out = excl + v;           // row_ptr[N] = grand total
}

__global__ void add_offsets(const int* __restrict__ local,
                            const int* __restrict__ partials,
                            int* __restrict__ row_ptr, int* __restrict__ cursor,
                            int Nn) {
  const int idx = blockIdx.x * 256 + threadIdx.x;
  if (idx < Nn) {
    int v = local[idx] + partials[blockIdx.x];
    row_ptr[idx] = v;
    cursor[idx] = v;
  }
}

// ---------------------------------------------------------------------------
static inline size_t align_up(size_t v) { return (v + 255) & ~(size_t)255; }

extern "C" void kernel_launch(void* const* d_in, const int* in_sizes, int n_in,
                              void* d_out, int out_size, void* d_ws, size_t ws_size,
                              hipStream_t stream) {
  const float* x      = (const float*)d_in[0];
  const int*   ei32   = (const int*)d_in[1];
  const float* W1     = (const float*)d_in[2];
  const float* asrc1  = (const float*)d_in[3];
  const float* adst1  = (const float*)d_in[4];
  const float* b1     = (const float*)d_in[5];
  const float* W2     = (const float*)d_in[6];
  const float* asrc2  = (const float*)d_in[7];
  const float* adst2  = (const float*)d_in[8];
  const float* b2     = (const float*)d_in[9];
  const float* W3     = (const float*)d_in[10];
  const float* asrc3  = (const float*)d_in[11];
  const float* adst3  = (const float*)d_in[12];
  const float* b3     = (const float*)d_in[13];

  const int N = in_sizes[0] / 128;   // 50000
  const int E = in_sizes[1] / 2;     // 800000
  const int ET = E + N;              // with self loops
  float* out = (float*)d_out;
  const int nb = (N + 255) / 256;

  // ---- workspace carve
  char* w = (char*)d_ws;
  float* H       = (float*)w; w += align_up((size_t)N * HC * sizeof(float));
  float* AS      = (float*)w; w += align_up((size_t)N * NHEAD * sizeof(float));
  float* AD      = (float*)w; w += align_up((size_t)N * NHEAD * sizeof(float));
  int*   cnt     = (int*)w;   w += align_up((size_t)N * sizeof(int));
  int*   local   = (int*)w;   w += align_up((size_t)N * sizeof(int));
  int*   row_ptr = (int*)w;   w += align_up((size_t)(N + 1) * sizeof(int));
  int*   cursor  = (int*)w;   w += align_up((size_t)(N + 1) * sizeof(int));
  int*   parts   = (int*)w;   w += align_up(256 * sizeof(int));
  int*   csr_src = (int*)w;   w += align_up((size_t)ET * sizeof(int));
  u16*   Wth     = (u16*)w;   w += align_up((size_t)256 * 256 * sizeof(u16));
  u16*   Wtl     = (u16*)w;   w += align_up((size_t)256 * 256 * sizeof(u16));
  int*   flag    = (int*)w;   w += align_up(sizeof(int));

  // ---- CSR build (dst-grouped), once per call
  hipMemsetAsync(cnt, 0, (size_t)N * sizeof(int), stream);
  detect_kernel<<<1, 64, 0, stream>>>(ei32, flag);
  count_kernel<<<(ET + 255) / 256, 256, 0, stream>>>(ei32, flag, cnt, E, N);
  scan_blocks<<<nb, 256, 0, stream>>>(cnt, local, parts, N);
  scan_partials<<<1, 256, 0, stream>>>(parts, nb, row_ptr + N);
  add_offsets<<<nb, 256, 0, stream>>>(local, parts, row_ptr, cursor, N);
  scatter_kernel<<<(ET + 255) / 256, 256, 0, stream>>>(ei32, flag, cursor, csr_src, E, N);

  const dim3 gemm_grid((N + GBM - 1) / GBM, HC / GBN);
  const int ablk = (N + 3) / 4;

  // ---- layer 1 (K=128), ReLU
  convert_w<<<(128 * 256 + 255) / 256, 256, 0, stream>>>(W1, Wth, Wtl, 128);
  gemm_mfma<<<gemm_grid, 256, 0, stream>>>(x, Wth, Wtl, H, N, 128);
  alpha_kernel<<<ablk, 256, 0, stream>>>(H, asrc1, adst1, AS, AD, N);
  aggregate_kernel<<<ablk, 256, 0, stream>>>(H, AS, AD, row_ptr, csr_src, b1, out, 1, N);

  // ---- layer 2 (K=256), ReLU
  convert_w<<<(256 * 256 + 255) / 256, 256, 0, stream>>>(W2, Wth, Wtl, 256);
  gemm_mfma<<<gemm_grid, 256, 0, stream>>>(out, Wth, Wtl, H, N, 256);
  alpha_kernel<<<ablk, 256, 0, stream>>>(H, asrc2, adst2, AS, AD, N);
  aggregate_kernel<<<ablk, 256, 0, stream>>>(H, AS, AD, row_ptr, csr_src, b2, out, 1, N);

  // ---- layer 3 (K=256), no ReLU
  convert_w<<<(256 * 256 + 255) / 256, 256, 0, stream>>>(W3, Wth, Wtl, 256);
  gemm_mfma<<<gemm_grid, 256, 0, stream>>>(out, Wth, Wtl, H, N, 256);
  alpha_kernel<<<ablk, 256, 0, stream>>>(H, asrc3, adst3, AS, AD, N);
  aggregate_kernel<<<ablk, 256, 0, stream>>>(H, AS, AD, row_ptr, csr_src, b3, out, 0, N);
}